// Round 2
// baseline (1617.231 us; speedup 1.0000x reference)
//
#include <hip/hip_runtime.h>
#include <hip/hip_bf16.h>
#include <cstdint>

// MMoE: B=16384, F=1024, E=8, U=512, EH=1024/1024, TH=512/256, T=4
#define B_ 16384
#define F_ 1024
#define E_ 8
#define U_ 512
#define EH1_ 1024
#define EH2_ 1024
#define TH1_ 512
#define TH2_ 256
#define T_ 4

typedef __attribute__((ext_vector_type(4))) float f32x4;
typedef __attribute__((ext_vector_type(8))) short bf16x8;
typedef __attribute__((ext_vector_type(4))) short s16x4;

__device__ __forceinline__ short f2bf(float f) {
  union { float f; unsigned u; } v; v.f = f;
  unsigned r = v.u + 0x7fffu + ((v.u >> 16) & 1u);  // RNE
  return (short)(r >> 16);
}
__device__ __forceinline__ float bf2f(short s) {
  union { unsigned u; float f; } v; v.u = ((unsigned)(unsigned short)s) << 16;
  return v.f;
}

__device__ __forceinline__ void gload16(const void* g, void* l) {
  __builtin_amdgcn_global_load_lds(
      (const __attribute__((address_space(1))) void*)g,
      (__attribute__((address_space(3))) void*)l, 16, 0, 0);
}

// ---------------- fp32 -> bf16 elementwise ----------------
__global__ __launch_bounds__(256) void conv_bf16(const float* __restrict__ in,
                                                 short* __restrict__ out, long n) {
  long i = ((long)blockIdx.x * 256 + threadIdx.x) * 8;
  if (i >= n) return;
  const float4* p = (const float4*)(in + i);
  float4 a = p[0], b = p[1];
  bf16x8 o;
  o[0] = f2bf(a.x); o[1] = f2bf(a.y); o[2] = f2bf(a.z); o[3] = f2bf(a.w);
  o[4] = f2bf(b.x); o[5] = f2bf(b.y); o[6] = f2bf(b.z); o[7] = f2bf(b.w);
  *(bf16x8*)(out + i) = o;
}

// ---------------- fp32 [E][K][N] -> bf16 [E][N][K] (transpose-convert) ----------------
__global__ __launch_bounds__(256) void trans_conv(const float* __restrict__ W,
                                                  short* __restrict__ Wt, int K, int N) {
  __shared__ float tile[32][33];
  const int e = blockIdx.z;
  const int k0 = blockIdx.x * 32, n0 = blockIdx.y * 32;
  const float* We = W + (size_t)e * K * N;
  short* Wte = Wt + (size_t)e * N * K;
  const int tx = threadIdx.x, ty = threadIdx.y;  // block (32,8)
#pragma unroll
  for (int r = 0; r < 32; r += 8)
    tile[ty + r][tx] = We[(size_t)(k0 + ty + r) * N + (n0 + tx)];
  __syncthreads();
#pragma unroll
  for (int r = 0; r < 32; r += 8)
    Wte[(size_t)(n0 + ty + r) * K + (k0 + tx)] = f2bf(tile[tx][ty + r]);
}

// ---------------- bf16 GEMM: C[M][N] = A[M][K] * Bt[N][K]^T + bias (opt ReLU) --------
// m97 structure: 128x128 tile, BK=32, 4 waves (2x2), 4x4 16x16x32 frags/wave,
// global_load_lds width-16 staging, 2 barriers per K-step.
template <int RELU>
__global__ __launch_bounds__(256, 2) void gemm_bt(const short* __restrict__ A,
                                                  const short* __restrict__ Bt,
                                                  const float* __restrict__ bias,
                                                  short* __restrict__ C,
                                                  int M, int N, int K) {
  __shared__ short As[128 * 32];
  __shared__ short Bs[128 * 32];
  const int tid = threadIdx.x;
  const int wid = tid >> 6;
  const int lane = tid & 63;
  const int m0 = blockIdx.x * 128;
  const int n0 = blockIdx.y * 128;
  const int wm = (wid >> 1) * 64;
  const int wn = (wid & 1) * 64;

  f32x4 acc[4][4];
#pragma unroll
  for (int i = 0; i < 4; i++)
#pragma unroll
    for (int j = 0; j < 4; j++)
#pragma unroll
      for (int r = 0; r < 4; r++) acc[i][j][r] = 0.f;

  // staging: wave w covers 16 rows per buffer-half; lane l -> LDS byte w*1024 + l*16
  const int srow = wid * 16 + (lane >> 2);
  const int scol = (lane & 3) * 8;
  const short* aSrc = A + (size_t)(m0 + srow) * K + scol;
  const short* bSrc = Bt + (size_t)(n0 + srow) * K + scol;
  short* aDst = As + wid * 512;
  short* bDst = Bs + wid * 512;
  const size_t halfoff = (size_t)64 * K;

  const int fr = lane & 15;
  const int kg = (lane >> 4) * 8;

  for (int k0 = 0; k0 < K; k0 += 32) {
    gload16(aSrc + k0, aDst);
    gload16(aSrc + halfoff + k0, aDst + 2048);
    gload16(bSrc + k0, bDst);
    gload16(bSrc + halfoff + k0, bDst + 2048);
    __syncthreads();
    bf16x8 af[4], bfv[4];
#pragma unroll
    for (int i = 0; i < 4; i++) af[i] = *(const bf16x8*)&As[(wm + i * 16 + fr) * 32 + kg];
#pragma unroll
    for (int j = 0; j < 4; j++) bfv[j] = *(const bf16x8*)&Bs[(wn + j * 16 + fr) * 32 + kg];
#pragma unroll
    for (int i = 0; i < 4; i++)
#pragma unroll
      for (int j = 0; j < 4; j++)
        acc[i][j] = __builtin_amdgcn_mfma_f32_16x16x32_bf16(af[i], bfv[j], acc[i][j], 0, 0, 0);
    __syncthreads();
  }

  // epilogue: C/D map col=lane&15, row=(lane>>4)*4+reg  [m89-verified]
  const int cr4 = (lane >> 4) * 4;
  const int cc = lane & 15;
#pragma unroll
  for (int j = 0; j < 4; j++) {
    const int col = n0 + wn + j * 16 + cc;
    const float bv = bias[col];
#pragma unroll
    for (int i = 0; i < 4; i++) {
      const int row = m0 + wm + i * 16 + cr4;
#pragma unroll
      for (int r = 0; r < 4; r++) {
        float v = acc[i][j][r] + bv;
        if (RELU) v = fmaxf(v, 0.f);
        C[(size_t)(row + r) * N + col] = f2bf(v);
      }
    }
  }
}

// ---------------- gates: fp32 logits + softmax over E (full B, once) ----------------
__global__ __launch_bounds__(256) void gates_kernel(const float* __restrict__ x,
                                                    const float* __restrict__ Wg,
                                                    float* __restrict__ gates) {
  const int wid = threadIdx.x >> 6, lane = threadIdx.x & 63;
  const int b = blockIdx.x * 4 + wid;
  const float* xb = x + (size_t)b * F_;
  float xv[16];
#pragma unroll
  for (int j = 0; j < 16; j++) xv[j] = xb[j * 64 + lane];
  float part[32];
#pragma unroll
  for (int t = 0; t < T_; t++)
#pragma unroll
    for (int e = 0; e < E_; e++) {
      float s = 0.f;
#pragma unroll
      for (int j = 0; j < 16; j++)
        s += xv[j] * Wg[((size_t)t * F_ + j * 64 + lane) * E_ + e];
      part[t * 8 + e] = s;
    }
#pragma unroll
  for (int i = 0; i < 32; i++)
#pragma unroll
    for (int off = 32; off; off >>= 1) part[i] += __shfl_xor(part[i], off, 64);
  if (lane < T_) {
    const int t = lane;
    float mx = -1e30f;
#pragma unroll
    for (int e = 0; e < E_; e++) mx = fmaxf(mx, part[t * 8 + e]);
    float ex[E_], den = 0.f;
#pragma unroll
    for (int e = 0; e < E_; e++) { ex[e] = __expf(part[t * 8 + e] - mx); den += ex[e]; }
    const float inv = 1.f / den;
#pragma unroll
    for (int e = 0; e < E_; e++) gates[((size_t)t * B_ + b) * E_ + e] = ex[e] * inv;
  }
}

// ---- combine (per chunk): ti[t][lb][u] = sum_e gates[t][b0+lb][e]*EO[e][lb][u] ----
__global__ __launch_bounds__(256) void combine_kernel(const short* __restrict__ EO,
                                                      const float* __restrict__ gates,
                                                      short* __restrict__ ti,
                                                      int Bc, int b0) {
  const int idx = blockIdx.x * 256 + threadIdx.x;  // lb*64 + uc/8
  const int lb = idx >> 6;
  const int uc = (idx & 63) * 8;
  float acc[T_][8];
#pragma unroll
  for (int t = 0; t < T_; t++)
#pragma unroll
    for (int j = 0; j < 8; j++) acc[t][j] = 0.f;
#pragma unroll
  for (int e = 0; e < E_; e++) {
    bf16x8 v = *(const bf16x8*)&EO[((size_t)e * Bc + lb) * U_ + uc];
    float f[8];
#pragma unroll
    for (int j = 0; j < 8; j++) f[j] = bf2f(v[j]);
#pragma unroll
    for (int t = 0; t < T_; t++) {
      const float g = gates[((size_t)t * B_ + b0 + lb) * E_ + e];
#pragma unroll
      for (int j = 0; j < 8; j++) acc[t][j] += g * f[j];
    }
  }
#pragma unroll
  for (int t = 0; t < T_; t++) {
    bf16x8 o;
#pragma unroll
    for (int j = 0; j < 8; j++) o[j] = f2bf(acc[t][j]);
    *(bf16x8*)&ti[((size_t)t * Bc + lb) * U_ + uc] = o;
  }
}

// ---- tower3 (per chunk): out[t*B + b0+lb] = dot(G2[t*Bc+lb], Wt3[t]) + bt3[t] ----
__global__ __launch_bounds__(256) void tower3_kernel(const short* __restrict__ G2,
                                                     const float* __restrict__ Wt3,
                                                     const float* __restrict__ bt3,
                                                     float* __restrict__ out,
                                                     int bcShift, int b0) {
  const int wid = threadIdx.x >> 6, lane = threadIdx.x & 63;
  const int rowl = blockIdx.x * 4 + wid;   // [0, T*Bc)
  const int t = rowl >> bcShift;
  const int lb = rowl & ((1 << bcShift) - 1);
  const short* g = G2 + (size_t)rowl * TH2_;
  s16x4 gv = *(const s16x4*)(g + lane * 4);
  float4 wv = *(const float4*)(Wt3 + t * TH2_ + lane * 4);
  float s = bf2f(gv[0]) * wv.x + bf2f(gv[1]) * wv.y + bf2f(gv[2]) * wv.z + bf2f(gv[3]) * wv.w;
#pragma unroll
  for (int off = 32; off; off >>= 1) s += __shfl_xor(s, off, 64);
  if (lane == 0) out[(size_t)t * B_ + b0 + lb] = s + bt3[t];
}

extern "C" void kernel_launch(void* const* d_in, const int* in_sizes, int n_in,
                              void* d_out, int out_size, void* d_ws, size_t ws_size,
                              hipStream_t stream) {
  const float* x   = (const float*)d_in[0];
  const float* We1 = (const float*)d_in[1];
  const float* be1 = (const float*)d_in[2];
  const float* We2 = (const float*)d_in[3];
  const float* be2 = (const float*)d_in[4];
  const float* We3 = (const float*)d_in[5];
  const float* be3 = (const float*)d_in[6];
  const float* Wg  = (const float*)d_in[7];
  const float* Wt1 = (const float*)d_in[8];
  const float* bt1 = (const float*)d_in[9];
  const float* Wt2 = (const float*)d_in[10];
  const float* bt2 = (const float*)d_in[11];
  const float* Wt3 = (const float*)d_in[12];
  const float* bt3 = (const float*)d_in[13];
  float* out = (float*)d_out;
  (void)in_sizes; (void)n_in; (void)out_size;

  char* ws = (char*)d_ws;
  size_t off = 0;
  auto alloc = [&](size_t bytes) {
    char* p = ws + off;
    off += (bytes + 255) & ~(size_t)255;
    return p;
  };
  // ---- persistent region (~47 MB) ----
  short* We1b  = (short*)alloc((size_t)E_ * F_ * EH1_ * 2);
  short* We2b  = (short*)alloc((size_t)E_ * EH1_ * EH2_ * 2);
  short* We3b  = (short*)alloc((size_t)E_ * EH2_ * U_ * 2);
  short* Wt1b  = (short*)alloc((size_t)T_ * U_ * TH1_ * 2);
  short* Wt2b  = (short*)alloc((size_t)T_ * TH1_ * TH2_ * 2);
  float* gates = (float*)alloc((size_t)T_ * B_ * E_ * 4);
  const size_t persist = off;

  // ---- chunk size: largest Bc <= 8192 whose chunk region fits ws_size ----
  int Bc = 8192;
  while (Bc > 128 && persist + (size_t)Bc * 18432 + 8192 > ws_size) Bc >>= 1;
  const int bcShift = __builtin_ctz((unsigned)Bc);

  short* xbc = (short*)alloc((size_t)Bc * F_ * 2);
  short* h1  = (short*)alloc((size_t)Bc * EH1_ * 2);
  short* h2  = (short*)alloc((size_t)Bc * EH2_ * 2);
  short* EOc = (short*)alloc((size_t)E_ * Bc * U_ * 2);
  short* tic = (short*)alloc((size_t)T_ * Bc * U_ * 2);
  // towers overlay the (dead after combine) EO chunk region
  short* G1 = EOc;                              // T*Bc*TH1 shorts
  short* G2 = EOc + (size_t)T_ * Bc * TH1_;     // T*Bc*TH2 shorts

  // ---- weight conversions (once) ----
  dim3 tb(32, 8);
  trans_conv<<<dim3(F_ / 32, EH1_ / 32, E_), tb, 0, stream>>>(We1, We1b, F_, EH1_);
  trans_conv<<<dim3(EH1_ / 32, EH2_ / 32, E_), tb, 0, stream>>>(We2, We2b, EH1_, EH2_);
  trans_conv<<<dim3(EH2_ / 32, U_ / 32, E_), tb, 0, stream>>>(We3, We3b, EH2_, U_);
  trans_conv<<<dim3(U_ / 32, TH1_ / 32, T_), tb, 0, stream>>>(Wt1, Wt1b, U_, TH1_);
  trans_conv<<<dim3(TH1_ / 32, TH2_ / 32, T_), tb, 0, stream>>>(Wt2, Wt2b, TH1_, TH2_);

  // ---- fp32 gates (softmax over experts), full B ----
  gates_kernel<<<B_ / 4, 256, 0, stream>>>(x, Wg, gates);

  // ---- chunked main pipeline ----
  for (int b0 = 0; b0 < B_; b0 += Bc) {
    conv_bf16<<<(Bc * (F_ / 8)) / 256, 256, 0, stream>>>(x + (size_t)b0 * F_, xbc,
                                                         (long)Bc * F_);
    for (int e = 0; e < E_; ++e) {
      gemm_bt<1><<<dim3(Bc / 128, EH1_ / 128), 256, 0, stream>>>(
          xbc, We1b + (size_t)e * F_ * EH1_, be1 + e * EH1_, h1, Bc, EH1_, F_);
      gemm_bt<1><<<dim3(Bc / 128, EH2_ / 128), 256, 0, stream>>>(
          h1, We2b + (size_t)e * EH1_ * EH2_, be2 + e * EH2_, h2, Bc, EH2_, EH1_);
      gemm_bt<0><<<dim3(Bc / 128, U_ / 128), 256, 0, stream>>>(
          h2, We3b + (size_t)e * EH2_ * U_, be3 + e * U_, EOc + (size_t)e * Bc * U_,
          Bc, U_, EH2_);
    }
    combine_kernel<<<(Bc * 64) / 256, 256, 0, stream>>>(EOc, gates, tic, Bc, b0);
    for (int t = 0; t < T_; ++t) {
      gemm_bt<1><<<dim3(Bc / 128, TH1_ / 128), 256, 0, stream>>>(
          tic + (size_t)t * Bc * U_, Wt1b + (size_t)t * U_ * TH1_, bt1 + t * TH1_,
          G1 + (size_t)t * Bc * TH1_, Bc, TH1_, U_);
      gemm_bt<1><<<dim3(Bc / 128, TH2_ / 128), 256, 0, stream>>>(
          G1 + (size_t)t * Bc * TH1_, Wt2b + (size_t)t * TH1_ * TH2_, bt2 + t * TH2_,
          G2 + (size_t)t * Bc * TH2_, Bc, TH2_, TH1_);
    }
    tower3_kernel<<<T_ * Bc / 4, 256, 0, stream>>>(G2, Wt3, bt3, out, bcShift, b0);
  }
}

// Round 3
// 1144.866 us; speedup vs baseline: 1.4126x; 1.4126x over previous
//
#include <hip/hip_runtime.h>
#include <hip/hip_bf16.h>
#include <cstdint>

// MMoE: B=16384, F=1024, E=8, U=512, EH=1024/1024, TH=512/256, T=4
#define B_ 16384
#define F_ 1024
#define E_ 8
#define U_ 512
#define EH1_ 1024
#define EH2_ 1024
#define TH1_ 512
#define TH2_ 256
#define T_ 4

typedef __attribute__((ext_vector_type(4))) float f32x4;
typedef __attribute__((ext_vector_type(8))) short bf16x8;
typedef __attribute__((ext_vector_type(4))) short s16x4;

__device__ __forceinline__ short f2bf(float f) {
  union { float f; unsigned u; } v; v.f = f;
  unsigned r = v.u + 0x7fffu + ((v.u >> 16) & 1u);  // RNE
  return (short)(r >> 16);
}
__device__ __forceinline__ float bf2f(short s) {
  union { unsigned u; float f; } v; v.u = ((unsigned)(unsigned short)s) << 16;
  return v.f;
}

__device__ __forceinline__ void gload16(const void* g, void* l) {
  __builtin_amdgcn_global_load_lds(
      (const __attribute__((address_space(1))) void*)g,
      (__attribute__((address_space(3))) void*)l, 16, 0, 0);
}

// ---- fp32 -> (bf16 main, bf16 residual) elementwise, 8/thread ----
__global__ __launch_bounds__(256) void conv_dual(const float* __restrict__ in,
                                                 short* __restrict__ ob,
                                                 short* __restrict__ orr, long n) {
  long i = ((long)blockIdx.x * 256 + threadIdx.x) * 8;
  if (i >= n) return;
  const float4* p = (const float4*)(in + i);
  float4 a = p[0], b = p[1];
  float v[8] = {a.x, a.y, a.z, a.w, b.x, b.y, b.z, b.w};
  bf16x8 o, r;
#pragma unroll
  for (int j = 0; j < 8; j++) {
    short s = f2bf(v[j]);
    o[j] = s;
    r[j] = f2bf(v[j] - bf2f(s));
  }
  *(bf16x8*)(ob + i) = o;
  *(bf16x8*)(orr + i) = r;
}

// ---- fp32 [Z][K][N] -> bf16 [Z][N][K] (transpose-convert) ----
__global__ __launch_bounds__(256) void trans_conv(const float* __restrict__ W,
                                                  short* __restrict__ Wt, int K, int N) {
  __shared__ float tile[32][33];
  const int e = blockIdx.z;
  const int k0 = blockIdx.x * 32, n0 = blockIdx.y * 32;
  const float* We = W + (size_t)e * K * N;
  short* Wte = Wt + (size_t)e * N * K;
  const int tx = threadIdx.x, ty = threadIdx.y;  // block (32,8)
#pragma unroll
  for (int r = 0; r < 32; r += 8)
    tile[ty + r][tx] = We[(size_t)(k0 + ty + r) * N + (n0 + tx)];
  __syncthreads();
#pragma unroll
  for (int r = 0; r < 32; r += 8)
    Wte[(size_t)(n0 + ty + r) * K + (k0 + tx)] = f2bf(tile[tx][ty + r]);
}

// ---- Wg[T][F][E] fp32 -> pair-major bf16 Wp[32][F] + residual Wr[32][F] ----
__global__ __launch_bounds__(256) void trans_wg(const float* __restrict__ Wg,
                                                short* __restrict__ Wp,
                                                short* __restrict__ Wr) {
  int idx = blockIdx.x * 256 + threadIdx.x;  // 32*1024
  int p = idx >> 10, f = idx & 1023;
  int t = p >> 3, e = p & 7;
  float w = Wg[((size_t)t * F_ + f) * E_ + e];
  short wb = f2bf(w);
  Wp[idx] = wb;
  Wr[idx] = f2bf(w - bf2f(wb));
}

// ---- gate logits via 3-term bf16 MFMA + fused softmax over E ----
// logits = xb*Wp + xb*Wr + xr*Wp  (error ~2e-4 absolute on sigma=32 logits)
// wave handles 16 rows x 32 pairs; grid = B/64 blocks of 4 waves.
__global__ __launch_bounds__(256) void glogits(const short* __restrict__ xb,
                                               const short* __restrict__ xr,
                                               const short* __restrict__ Wp,
                                               const short* __restrict__ Wr,
                                               float* __restrict__ gates) {
  const int wid = threadIdx.x >> 6, lane = threadIdx.x & 63;
  const int m0 = blockIdx.x * 64 + wid * 16;
  const int fr = lane & 15, kg = (lane >> 4) * 8;
  f32x4 acc[2];
#pragma unroll
  for (int j = 0; j < 2; j++)
#pragma unroll
    for (int r = 0; r < 4; r++) acc[j][r] = 0.f;

  const short* Aterm[3] = {xb, xb, xr};
  const short* Bterm[3] = {Wp, Wr, Wp};
#pragma unroll
  for (int term = 0; term < 3; ++term) {
    const short* A = Aterm[term] + (size_t)(m0 + fr) * F_ + kg;
    const short* Bt0 = Bterm[term] + (size_t)fr * F_ + kg;
    const short* Bt1 = Bterm[term] + (size_t)(16 + fr) * F_ + kg;
    for (int k0 = 0; k0 < F_; k0 += 32) {
      bf16x8 a = *(const bf16x8*)(A + k0);
      bf16x8 b0 = *(const bf16x8*)(Bt0 + k0);
      bf16x8 b1 = *(const bf16x8*)(Bt1 + k0);
      acc[0] = __builtin_amdgcn_mfma_f32_16x16x32_bf16(a, b0, acc[0], 0, 0, 0);
      acc[1] = __builtin_amdgcn_mfma_f32_16x16x32_bf16(a, b1, acc[1], 0, 0, 0);
    }
  }
  // C/D: col = lane&15 (pair within frag), row = (lane>>4)*4 + r
  const int cc = lane & 15;
#pragma unroll
  for (int j = 0; j < 2; ++j) {
    const int t = j * 2 + (cc >> 3), e = cc & 7;
#pragma unroll
    for (int r = 0; r < 4; ++r) {
      float s = acc[j][r];
      float mx = s;
      mx = fmaxf(mx, __shfl_xor(mx, 1, 64));
      mx = fmaxf(mx, __shfl_xor(mx, 2, 64));
      mx = fmaxf(mx, __shfl_xor(mx, 4, 64));
      float ex = __expf(s - mx);
      float sm = ex;
      sm += __shfl_xor(sm, 1, 64);
      sm += __shfl_xor(sm, 2, 64);
      sm += __shfl_xor(sm, 4, 64);
      const int b = m0 + (lane >> 4) * 4 + r;
      gates[((size_t)t * B_ + b) * E_ + e] = ex / sm;
    }
  }
}

// ---- z-batched bf16 GEMM: C[z] = A[z][M][K] * Bt[z][N][K]^T + bias[z] ----
// m97 structure: 128x128 tile, BK=32, 4 waves, global_load_lds width-16.
template <int RELU>
__global__ __launch_bounds__(256, 2) void gemm_bt(const short* __restrict__ A0, size_t sA,
                                                  const short* __restrict__ B0, size_t sB,
                                                  const float* __restrict__ bias0, size_t sBias,
                                                  short* __restrict__ C0, size_t sC,
                                                  int M, int N, int K) {
  const int z = blockIdx.z;
  const short* A = A0 + (size_t)z * sA;
  const short* Bt = B0 + (size_t)z * sB;
  const float* bias = bias0 + (size_t)z * sBias;
  short* C = C0 + (size_t)z * sC;

  __shared__ short As[128 * 32];
  __shared__ short Bs[128 * 32];
  const int tid = threadIdx.x;
  const int wid = tid >> 6;
  const int lane = tid & 63;
  const int m0 = blockIdx.x * 128;
  const int n0 = blockIdx.y * 128;
  const int wm = (wid >> 1) * 64;
  const int wn = (wid & 1) * 64;

  f32x4 acc[4][4];
#pragma unroll
  for (int i = 0; i < 4; i++)
#pragma unroll
    for (int j = 0; j < 4; j++)
#pragma unroll
      for (int r = 0; r < 4; r++) acc[i][j][r] = 0.f;

  const int srow = wid * 16 + (lane >> 2);
  const int scol = (lane & 3) * 8;
  const short* aSrc = A + (size_t)(m0 + srow) * K + scol;
  const short* bSrc = Bt + (size_t)(n0 + srow) * K + scol;
  short* aDst = As + wid * 512;
  short* bDst = Bs + wid * 512;
  const size_t halfoff = (size_t)64 * K;

  const int fr = lane & 15;
  const int kg = (lane >> 4) * 8;

  for (int k0 = 0; k0 < K; k0 += 32) {
    gload16(aSrc + k0, aDst);
    gload16(aSrc + halfoff + k0, aDst + 2048);
    gload16(bSrc + k0, bDst);
    gload16(bSrc + halfoff + k0, bDst + 2048);
    __syncthreads();
    bf16x8 af[4], bfv[4];
#pragma unroll
    for (int i = 0; i < 4; i++) af[i] = *(const bf16x8*)&As[(wm + i * 16 + fr) * 32 + kg];
#pragma unroll
    for (int j = 0; j < 4; j++) bfv[j] = *(const bf16x8*)&Bs[(wn + j * 16 + fr) * 32 + kg];
#pragma unroll
    for (int i = 0; i < 4; i++)
#pragma unroll
      for (int j = 0; j < 4; j++)
        acc[i][j] = __builtin_amdgcn_mfma_f32_16x16x32_bf16(af[i], bfv[j], acc[i][j], 0, 0, 0);
    __syncthreads();
  }

  const int cr4 = (lane >> 4) * 4;
  const int cc = lane & 15;
#pragma unroll
  for (int j = 0; j < 4; j++) {
    const int col = n0 + wn + j * 16 + cc;
    const float bv = bias[col];
#pragma unroll
    for (int i = 0; i < 4; i++) {
      const int row = m0 + wm + i * 16 + cr4;
#pragma unroll
      for (int r = 0; r < 4; r++) {
        float v = acc[i][j][r] + bv;
        if (RELU) v = fmaxf(v, 0.f);
        C[(size_t)(row + r) * N + col] = f2bf(v);
      }
    }
  }
}

// ---- combine (per chunk): ti[t][lb][u] = sum_e gates[t][b0+lb][e]*EO[e][lb][u] ----
__global__ __launch_bounds__(256) void combine_kernel(const short* __restrict__ EO,
                                                      const float* __restrict__ gates,
                                                      short* __restrict__ ti,
                                                      int Bc, int b0) {
  const int idx = blockIdx.x * 256 + threadIdx.x;  // lb*64 + uc/8
  const int lb = idx >> 6;
  const int uc = (idx & 63) * 8;
  float acc[T_][8];
#pragma unroll
  for (int t = 0; t < T_; t++)
#pragma unroll
    for (int j = 0; j < 8; j++) acc[t][j] = 0.f;
#pragma unroll
  for (int e = 0; e < E_; e++) {
    bf16x8 v = *(const bf16x8*)&EO[((size_t)e * Bc + lb) * U_ + uc];
    float f[8];
#pragma unroll
    for (int j = 0; j < 8; j++) f[j] = bf2f(v[j]);
#pragma unroll
    for (int t = 0; t < T_; t++) {
      const float g = gates[((size_t)t * B_ + b0 + lb) * E_ + e];
#pragma unroll
      for (int j = 0; j < 8; j++) acc[t][j] += g * f[j];
    }
  }
#pragma unroll
  for (int t = 0; t < T_; t++) {
    bf16x8 o;
#pragma unroll
    for (int j = 0; j < 8; j++) o[j] = f2bf(acc[t][j]);
    *(bf16x8*)&ti[((size_t)t * Bc + lb) * U_ + uc] = o;
  }
}

// ---- tower3: out[t*B + b0+lb] = dot(G2[t*Bc+lb], Wt3[t]) + bt3[t] ----
__global__ __launch_bounds__(256) void tower3_kernel(const short* __restrict__ G2,
                                                     const float* __restrict__ Wt3,
                                                     const float* __restrict__ bt3,
                                                     float* __restrict__ out,
                                                     int bcShift, int b0) {
  const int wid = threadIdx.x >> 6, lane = threadIdx.x & 63;
  const int rowl = blockIdx.x * 4 + wid;  // [0, T*Bc)
  const int t = rowl >> bcShift;
  const int lb = rowl & ((1 << bcShift) - 1);
  const short* g = G2 + (size_t)rowl * TH2_;
  s16x4 gv = *(const s16x4*)(g + lane * 4);
  float4 wv = *(const float4*)(Wt3 + t * TH2_ + lane * 4);
  float s = bf2f(gv[0]) * wv.x + bf2f(gv[1]) * wv.y + bf2f(gv[2]) * wv.z + bf2f(gv[3]) * wv.w;
#pragma unroll
  for (int off = 32; off; off >>= 1) s += __shfl_xor(s, off, 64);
  if (lane == 0) out[(size_t)t * B_ + b0 + lb] = s + bt3[t];
}

extern "C" void kernel_launch(void* const* d_in, const int* in_sizes, int n_in,
                              void* d_out, int out_size, void* d_ws, size_t ws_size,
                              hipStream_t stream) {
  const float* x   = (const float*)d_in[0];
  const float* We1 = (const float*)d_in[1];
  const float* be1 = (const float*)d_in[2];
  const float* We2 = (const float*)d_in[3];
  const float* be2 = (const float*)d_in[4];
  const float* We3 = (const float*)d_in[5];
  const float* be3 = (const float*)d_in[6];
  const float* Wg  = (const float*)d_in[7];
  const float* Wt1 = (const float*)d_in[8];
  const float* bt1 = (const float*)d_in[9];
  const float* Wt2 = (const float*)d_in[10];
  const float* bt2 = (const float*)d_in[11];
  const float* Wt3 = (const float*)d_in[12];
  const float* bt3 = (const float*)d_in[13];
  float* out = (float*)d_out;
  (void)in_sizes; (void)n_in; (void)out_size;

  char* ws = (char*)d_ws;
  size_t off = 0;
  auto alloc = [&](size_t bytes) {
    char* p = ws + off;
    off += (bytes + 255) & ~(size_t)255;
    return p;
  };
  // ---- persistent region (~114 MB) ----
  short* We1b  = (short*)alloc((size_t)E_ * F_ * EH1_ * 2);
  short* We2b  = (short*)alloc((size_t)E_ * EH1_ * EH2_ * 2);
  short* We3b  = (short*)alloc((size_t)E_ * EH2_ * U_ * 2);
  short* Wt1b  = (short*)alloc((size_t)T_ * U_ * TH1_ * 2);
  short* Wt2b  = (short*)alloc((size_t)T_ * TH1_ * TH2_ * 2);
  short* Wgp   = (short*)alloc((size_t)32 * F_ * 2);
  short* Wgr   = (short*)alloc((size_t)32 * F_ * 2);
  float* gates = (float*)alloc((size_t)T_ * B_ * E_ * 4);
  short* xb    = (short*)alloc((size_t)B_ * F_ * 2);
  short* xrb   = (short*)alloc((size_t)B_ * F_ * 2);
  const size_t persist = off;

  // ---- chunk sizing: per-row bytes = h1(16384) + h2(16384) + ti(4096) ----
  int Bc = 16384;
  while (Bc > 256 && persist + (size_t)Bc * 36864 + 65536 > ws_size) Bc >>= 1;
  const int bcShift = __builtin_ctz((unsigned)Bc);

  short* h1 = (short*)alloc((size_t)E_ * Bc * EH1_ * 2);  // also EO overlay
  short* h2 = (short*)alloc((size_t)E_ * Bc * EH2_ * 2);  // also G1/G2 overlay
  short* ti = (short*)alloc((size_t)T_ * Bc * U_ * 2);
  short* EO = h1;                              // E*Bc*U (8192*Bc B) <= h1 region
  short* G1 = h2;                              // T*Bc*TH1 (4096*Bc B)
  short* G2 = h2 + (size_t)T_ * Bc * TH1_;     // T*Bc*TH2 (2048*Bc B)

  // ---- one-time conversions ----
  conv_dual<<<(B_ * F_ / 8 + 255) / 256, 256, 0, stream>>>(x, xb, xrb, (long)B_ * F_);
  dim3 tb(32, 8);
  trans_conv<<<dim3(F_ / 32, EH1_ / 32, E_), tb, 0, stream>>>(We1, We1b, F_, EH1_);
  trans_conv<<<dim3(EH1_ / 32, EH2_ / 32, E_), tb, 0, stream>>>(We2, We2b, EH1_, EH2_);
  trans_conv<<<dim3(EH2_ / 32, U_ / 32, E_), tb, 0, stream>>>(We3, We3b, EH2_, U_);
  trans_conv<<<dim3(U_ / 32, TH1_ / 32, T_), tb, 0, stream>>>(Wt1, Wt1b, U_, TH1_);
  trans_conv<<<dim3(TH1_ / 32, TH2_ / 32, T_), tb, 0, stream>>>(Wt2, Wt2b, TH1_, TH2_);
  trans_wg<<<(32 * F_) / 256, 256, 0, stream>>>(Wg, Wgp, Wgr);

  // ---- gates: 3-term MFMA + fused softmax ----
  glogits<<<B_ / 64, 256, 0, stream>>>(xb, xrb, Wgp, Wgr, gates);

  // ---- chunked main pipeline (z-batched GEMMs) ----
  for (int b0 = 0; b0 < B_; b0 += Bc) {
    const short* xc = xb + (size_t)b0 * F_;
    gemm_bt<1><<<dim3(Bc / 128, EH1_ / 128, E_), 256, 0, stream>>>(
        xc, 0, We1b, (size_t)F_ * EH1_, be1, EH1_, h1, (size_t)Bc * EH1_, Bc, EH1_, F_);
    gemm_bt<1><<<dim3(Bc / 128, EH2_ / 128, E_), 256, 0, stream>>>(
        h1, (size_t)Bc * EH1_, We2b, (size_t)EH1_ * EH2_, be2, EH2_, h2, (size_t)Bc * EH2_,
        Bc, EH2_, EH1_);
    gemm_bt<0><<<dim3(Bc / 128, U_ / 128, E_), 256, 0, stream>>>(
        h2, (size_t)Bc * EH2_, We3b, (size_t)EH2_ * U_, be3, U_, EO, (size_t)Bc * U_,
        Bc, U_, EH2_);
    combine_kernel<<<(Bc * 64) / 256, 256, 0, stream>>>(EO, gates, ti, Bc, b0);
    gemm_bt<1><<<dim3(Bc / 128, TH1_ / 128, T_), 256, 0, stream>>>(
        ti, (size_t)Bc * U_, Wt1b, (size_t)U_ * TH1_, bt1, TH1_, G1, (size_t)Bc * TH1_,
        Bc, TH1_, U_);
    gemm_bt<1><<<dim3(Bc / 128, TH2_ / 128, T_), 256, 0, stream>>>(
        G1, (size_t)Bc * TH1_, Wt2b, (size_t)TH1_ * TH2_, bt2, TH2_, G2, (size_t)Bc * TH2_,
        Bc, TH2_, TH1_);
    tower3_kernel<<<T_ * Bc / 4, 256, 0, stream>>>(G2, Wt3, bt3, out, bcShift, b0);
  }
}